// Round 2
// baseline (153.180 us; speedup 1.0000x reference)
//
#include <hip/hip_runtime.h>

// CrumbReconstructor: for each 8-float block of x, find nearest codebook row
// (squared Euclidean over 256 rows of length 8), output that row.
//
// R1 strategy: the row loop is wave-uniform, so codebook values + norms are
// read with SCALAR loads (uniform address, __restrict__ -> s_load) and enter
// the dot product as SGPR operands of v_fma_f32. The hot loop has zero LDS
// traffic and zero vector address math: 13 VALU instrs per (key,row) pair.
// Distance formula / order / tie-break are bit-identical to R0 (absmax was 0).

#define LBLK 8      // memblock length
#define NROW 256    // codebook rows
#define TPK 2       // key-blocks per thread
#define BLOCK 256   // threads per workgroup

// Prep: row norms into workspace so the main loop can scalar-load them.
// Must mimic numpy: elementwise square, then 8-wide (pairwise) tree sum.
__global__ __launch_bounds__(NROW) void prep_norms(
    const float* __restrict__ mem, float* __restrict__ norms)
{
    int t = threadIdx.x;  // one thread per row
    const float4* g = (const float4*)mem;
    float4 a = g[t * 2 + 0];
    float4 b = g[t * 2 + 1];
    float q0 = a.x * a.x, q1 = a.y * a.y, q2 = a.z * a.z, q3 = a.w * a.w;
    float q4 = b.x * b.x, q5 = b.y * b.y, q6 = b.z * b.z, q7 = b.w * b.w;
    norms[t] = ((q0 + q1) + (q2 + q3)) + ((q4 + q5) + (q6 + q7));
}

__global__ __launch_bounds__(BLOCK) void crumb_kernel(
    const float* __restrict__ x,
    const float* __restrict__ mem,
    const float* __restrict__ norms,
    float* __restrict__ out,
    int nblocks)
{
    __shared__ float s_mem[NROW * LBLK];   // 8 KB codebook copy, used only for final gather
    const int tid = threadIdx.x;

    // stage codebook for the epilogue gather (divergent reads -> LDS, not global)
    {
        const float4* g = (const float4*)mem;
        ((float4*)s_mem)[tid * 2 + 0] = g[tid * 2 + 0];
        ((float4*)s_mem)[tid * 2 + 1] = g[tid * 2 + 1];
    }
    __syncthreads();

    const long base = (long)blockIdx.x * (BLOCK * TPK) + tid;

    float k[TPK][LBLK];
    float knorm[TPK];
    long  kb[TPK];
    bool  valid[TPK];

    #pragma unroll
    for (int t = 0; t < TPK; ++t) {
        long b0 = base + (long)t * BLOCK;
        valid[t] = (b0 < (long)nblocks);
        kb[t] = valid[t] ? b0 : (long)(nblocks - 1);
        const float4* g = (const float4*)(x + kb[t] * LBLK);
        float4 a = g[0], b = g[1];
        k[t][0] = a.x; k[t][1] = a.y; k[t][2] = a.z; k[t][3] = a.w;
        k[t][4] = b.x; k[t][5] = b.y; k[t][6] = b.z; k[t][7] = b.w;
        float q0 = a.x * a.x, q1 = a.y * a.y, q2 = a.z * a.z, q3 = a.w * a.w;
        float q4 = b.x * b.x, q5 = b.y * b.y, q6 = b.z * b.z, q7 = b.w * b.w;
        knorm[t] = ((q0 + q1) + (q2 + q3)) + ((q4 + q5) + (q6 + q7));
    }

    float best[TPK];
    int   bidx[TPK];
    #pragma unroll
    for (int t = 0; t < TPK; ++t) { best[t] = 3.4e38f; bidx[t] = 0; }

    // --- score all 256 rows; codebook via wave-uniform SCALAR loads ---
    #pragma unroll 4
    for (int m = 0; m < NROW; ++m) {
        const float* __restrict__ r = mem + m * LBLK;   // uniform address -> s_load
        float m0 = r[0], m1 = r[1], m2 = r[2], m3 = r[3];
        float m4 = r[4], m5 = r[5], m6 = r[6], m7 = r[7];
        float nrm = norms[m];                            // uniform -> s_load

        #pragma unroll
        for (int t = 0; t < TPK; ++t) {
            // sequential FMA dot, same order as R0 (bit-exact vs reference)
            float dot = k[t][0] * m0;
            dot = fmaf(k[t][1], m1, dot);
            dot = fmaf(k[t][2], m2, dot);
            dot = fmaf(k[t][3], m3, dot);
            dot = fmaf(k[t][4], m4, dot);
            dot = fmaf(k[t][5], m5, dot);
            dot = fmaf(k[t][6], m6, dot);
            dot = fmaf(k[t][7], m7, dot);
            float d = fmaf(dot, -2.0f, knorm[t]) + nrm;
            // strict < : first (lowest) index wins exact ties, matches argmin
            if (d < best[t]) { best[t] = d; bidx[t] = m; }
        }
    }

    // --- gather winning rows from LDS, store ---
    #pragma unroll
    for (int t = 0; t < TPK; ++t) {
        if (valid[t]) {
            float4* o = (float4*)(out + kb[t] * LBLK);
            o[0] = ((const float4*)s_mem)[bidx[t] * 2 + 0];
            o[1] = ((const float4*)s_mem)[bidx[t] * 2 + 1];
        }
    }
}

extern "C" void kernel_launch(void* const* d_in, const int* in_sizes, int n_in,
                              void* d_out, int out_size, void* d_ws, size_t ws_size,
                              hipStream_t stream) {
    const float* x   = (const float*)d_in[0];
    const float* mem = (const float*)d_in[1];
    float* out   = (float*)d_out;
    float* norms = (float*)d_ws;   // 256 floats of scratch

    int n = in_sizes[0];            // total x elements
    int nblocks = n / LBLK;         // key-blocks
    int grid = (nblocks + BLOCK * TPK - 1) / (BLOCK * TPK);

    hipLaunchKernelGGL(prep_norms, dim3(1), dim3(NROW), 0, stream, mem, norms);
    hipLaunchKernelGGL(crumb_kernel, dim3(grid), dim3(BLOCK), 0, stream,
                       x, mem, norms, out, nblocks);
}

// Round 3
// 133.778 us; speedup vs baseline: 1.1450x; 1.1450x over previous
//
#include <hip/hip_runtime.h>

// CrumbReconstructor: for each 8-float block of x, find nearest codebook row
// (squared Euclidean over 256 rows of length 8), output that row.
//
// R3: back to R0's LDS-broadcast structure (R2's scalar-load path stalled on
// lgkmcnt with no SGPR room to prefetch). Fix R0's real problem instead:
// VGPR_Count=36 left no registers to pipeline the per-row LDS reads, exposing
// ~120cyc ds_read latency per row group. Changes:
//   - __launch_bounds__(256, 2): lift VGPR cap (~60 needed, still 8 waves/SIMD)
//   - explicit 1-row-ahead register prefetch of row data (2xfloat4 + norm)
//   - hot-loop math bit-identical to R0 (absmax was 0.0)

#define LBLK 8      // memblock length
#define NROW 256    // codebook rows
#define TPK 2       // key-blocks per thread
#define BLOCK 256   // threads per workgroup

__global__ __launch_bounds__(BLOCK, 2) void crumb_kernel(
    const float* __restrict__ x,
    const float* __restrict__ mem,
    float* __restrict__ out,
    int nblocks)
{
    __shared__ float s_mem[NROW * LBLK];   // 8 KB, rows contiguous
    __shared__ float s_norm[NROW];         // 1 KB

    const int tid = threadIdx.x;

    // --- stage codebook: thread t loads row t, computes its norm ---
    {
        const float4* g = (const float4*)mem;
        float4 a = g[tid * 2 + 0];
        float4 b = g[tid * 2 + 1];
        ((float4*)s_mem)[tid * 2 + 0] = a;
        ((float4*)s_mem)[tid * 2 + 1] = b;
        // numpy order: elementwise square, 8-wide pairwise tree sum
        float q0 = a.x * a.x, q1 = a.y * a.y, q2 = a.z * a.z, q3 = a.w * a.w;
        float q4 = b.x * b.x, q5 = b.y * b.y, q6 = b.z * b.z, q7 = b.w * b.w;
        s_norm[tid] = ((q0 + q1) + (q2 + q3)) + ((q4 + q5) + (q6 + q7));
    }
    __syncthreads();

    const long base = (long)blockIdx.x * (BLOCK * TPK) + tid;

    float k[TPK][LBLK];
    float knorm[TPK];
    long  kb[TPK];
    bool  valid[TPK];

    #pragma unroll
    for (int t = 0; t < TPK; ++t) {
        long b0 = base + (long)t * BLOCK;
        valid[t] = (b0 < (long)nblocks);
        kb[t] = valid[t] ? b0 : 0;
        const float4* g = (const float4*)(x + kb[t] * LBLK);
        float4 a = g[0], b = g[1];
        k[t][0] = a.x; k[t][1] = a.y; k[t][2] = a.z; k[t][3] = a.w;
        k[t][4] = b.x; k[t][5] = b.y; k[t][6] = b.z; k[t][7] = b.w;
        float q0 = a.x * a.x, q1 = a.y * a.y, q2 = a.z * a.z, q3 = a.w * a.w;
        float q4 = b.x * b.x, q5 = b.y * b.y, q6 = b.z * b.z, q7 = b.w * b.w;
        knorm[t] = ((q0 + q1) + (q2 + q3)) + ((q4 + q5) + (q6 + q7));
    }

    float best[TPK];
    int   bidx[TPK];
    #pragma unroll
    for (int t = 0; t < TPK; ++t) { best[t] = 3.4e38f; bidx[t] = 0; }

    // --- score all 256 rows; explicit 1-row-ahead prefetch in registers ---
    float4 ra = ((const float4*)s_mem)[0];
    float4 rb = ((const float4*)s_mem)[1];
    float  rn = s_norm[0];

    #pragma unroll 4
    for (int m = 0; m < NROW; ++m) {
        // prefetch row m+1 (wraps to 0 on last iter; value unused)
        const int mn = (m + 1) & (NROW - 1);
        float4 na = ((const float4*)s_mem)[mn * 2 + 0];
        float4 nb = ((const float4*)s_mem)[mn * 2 + 1];
        float  nn = s_norm[mn];

        #pragma unroll
        for (int t = 0; t < TPK; ++t) {
            // sequential FMA dot, bit-identical to R0 (absmax 0)
            float dot = k[t][0] * ra.x;
            dot = fmaf(k[t][1], ra.y, dot);
            dot = fmaf(k[t][2], ra.z, dot);
            dot = fmaf(k[t][3], ra.w, dot);
            dot = fmaf(k[t][4], rb.x, dot);
            dot = fmaf(k[t][5], rb.y, dot);
            dot = fmaf(k[t][6], rb.z, dot);
            dot = fmaf(k[t][7], rb.w, dot);
            float d = fmaf(dot, -2.0f, knorm[t]) + rn;
            // strict < : first (lowest) index wins exact ties, matches argmin
            if (d < best[t]) { best[t] = d; bidx[t] = m; }
        }

        ra = na; rb = nb; rn = nn;
    }

    // --- gather winning rows from LDS, store ---
    #pragma unroll
    for (int t = 0; t < TPK; ++t) {
        if (valid[t]) {
            float4* o = (float4*)(out + kb[t] * LBLK);
            o[0] = ((const float4*)s_mem)[bidx[t] * 2 + 0];
            o[1] = ((const float4*)s_mem)[bidx[t] * 2 + 1];
        }
    }
}

extern "C" void kernel_launch(void* const* d_in, const int* in_sizes, int n_in,
                              void* d_out, int out_size, void* d_ws, size_t ws_size,
                              hipStream_t stream) {
    const float* x   = (const float*)d_in[0];
    const float* mem = (const float*)d_in[1];
    float* out = (float*)d_out;

    int n = in_sizes[0];            // total x elements
    int nblocks = n / LBLK;         // key-blocks
    int grid = (nblocks + BLOCK * TPK - 1) / (BLOCK * TPK);

    hipLaunchKernelGGL(crumb_kernel, dim3(grid), dim3(BLOCK), 0, stream,
                       x, mem, out, nblocks);
}